// Round 16
// baseline (117.759 us; speedup 1.0000x reference)
//
#include <hip/hip_runtime.h>
#include <math.h>

#define B_  2
#define L_  1024
#define D_  768
#define NH_ 12
#define HD_ 64
#define K_  24
#define R_  768
#define NC_ 16
#define CS_ 64

typedef __bf16 bf16x8 __attribute__((ext_vector_type(8)));
typedef float f32x4 __attribute__((ext_vector_type(4)));
typedef float f32x8 __attribute__((ext_vector_type(8)));
typedef unsigned short u16x8 __attribute__((ext_vector_type(8)));

__device__ inline unsigned short f2bf(float f) {
    union { float f; unsigned u; } v; v.f = f;
    unsigned r = v.u + 0x7FFFu + ((v.u >> 16) & 1u);
    return (unsigned short)(r >> 16);
}

__device__ inline ushort4 pack4(const f32x4 v) {
    ushort4 r;
    r.x = f2bf(v[0]); r.y = f2bf(v[1]); r.z = f2bf(v[2]); r.w = f2bf(v[3]);
    return r;
}

__device__ inline u16x8 pack8(const f32x8 v) {
    u16x8 r;
#pragma unroll
    for (int e = 0; e < 8; ++e) r[e] = f2bf(v[e]);
    return r;
}

__device__ inline f32x8 bf2f8(const u16x8 v) {
    f32x8 r;
#pragma unroll
    for (int e = 0; e < 8; ++e) {
        union { float f; unsigned u; } t;
        t.u = ((unsigned)v[e]) << 16;
        r[e] = t.f;
    }
    return r;
}

#define GLD_LDS16(g, l)                                                     \
    __builtin_amdgcn_global_load_lds(                                       \
        (const __attribute__((address_space(1))) void*)(g),                 \
        (__attribute__((address_space(3))) void*)(l), 16, 0, 0)

// ---------------------------------------------------------------------------
// k_prep: [0,864) weight transposes (6x 768x768 fp32 -> bf16 T)
//         [864,1632) x fp32 -> bf16
//         [1632,3168) phiev[n][r] = bf16(2 * sum_k stu[2n][k]*Mf[k][r])
// ---------------------------------------------------------------------------
__global__ __launch_bounds__(256) void k_prep(const float* __restrict__ w0,
                                              const float* __restrict__ w1,
                                              const float* __restrict__ w2,
                                              const float* __restrict__ w3,
                                              const float* __restrict__ w4,
                                              const float* __restrict__ w5,
                                              unsigned short* __restrict__ Wt,
                                              const float* __restrict__ x,
                                              unsigned short* __restrict__ xb,
                                              const float* __restrict__ F,
                                              const float* __restrict__ Mf,
                                              unsigned short* __restrict__ phiev) {
    const int bid = blockIdx.x;
    const int tid = threadIdx.x;
    if (bid < 864) {
        const int z = bid / 144, rem = bid % 144;
        const float* W;
        switch (z) {
            case 0: W = w0; break;
            case 1: W = w1; break;
            case 2: W = w2; break;
            case 3: W = w3; break;
            case 4: W = w4; break;
            default: W = w5; break;
        }
        unsigned short* o = Wt + (size_t)z * D_ * D_;
        __shared__ float t[64][69];
        const int n0 = (rem % 12) * 64, k0 = (rem / 12) * 64;
        const int row = tid >> 4, c4 = (tid & 15) * 4;
#pragma unroll
        for (int i = 0; i < 4; ++i) {
            const float4 v = *reinterpret_cast<const float4*>(
                W + (size_t)(k0 + row + i * 16) * D_ + n0 + c4);
            t[row + i * 16][c4 + 0] = v.x;
            t[row + i * 16][c4 + 1] = v.y;
            t[row + i * 16][c4 + 2] = v.z;
            t[row + i * 16][c4 + 3] = v.w;
        }
        __syncthreads();
#pragma unroll
        for (int i = 0; i < 4; ++i) {
            const int nn = row + i * 16;
            ushort4 o4;
            o4.x = f2bf(t[c4 + 0][nn]);
            o4.y = f2bf(t[c4 + 1][nn]);
            o4.z = f2bf(t[c4 + 2][nn]);
            o4.w = f2bf(t[c4 + 3][nn]);
            *reinterpret_cast<ushort4*>(o + (size_t)(n0 + nn) * D_ + k0 + c4) = o4;
        }
    } else if (bid < 1632) {
        const int i8 = ((bid - 864) * 256 + tid) * 8;
        float4 f0 = *reinterpret_cast<const float4*>(x + i8);
        float4 f1 = *reinterpret_cast<const float4*>(x + i8 + 4);
        u16x8 p;
        p[0] = f2bf(f0.x); p[1] = f2bf(f0.y); p[2] = f2bf(f0.z); p[3] = f2bf(f0.w);
        p[4] = f2bf(f1.x); p[5] = f2bf(f1.y); p[6] = f2bf(f1.z); p[7] = f2bf(f1.w);
        *reinterpret_cast<u16x8*>(xb + i8) = p;
    } else {
        const int idx = (bid - 1632) * 256 + tid;    // over 512*768
        const int r = idx % R_;
        const int n = idx / R_;
        float acc = 0.f;
#pragma unroll
        for (int kk = 0; kk < K_; ++kk)
            acc += F[(2 * n) * K_ + kk] * Mf[kk * R_ + r];
        phiev[idx] = f2bf(2.f * acc);
    }
}

// ---------------------------------------------------------------------------
// bf16 MFMA GEMM core, 2-phase double-buffered; static internal LDS.
// mode 1: bf16 row cbf; mode 2: bf16 transposed ct via LDS pack; 3: 1+2.
// ---------------------------------------------------------------------------
template <int FM, int FN>
__device__ __forceinline__ void gemm_core(const unsigned short* __restrict__ A,
                                          const unsigned short* __restrict__ Bt,
                                          const float* __restrict__ bias,
                                          int mode,
                                          unsigned short* __restrict__ cbf,
                                          unsigned short* __restrict__ ct,
                                          int Kd, int bm, int bn, int tid) {
    constexpr int BM = 2 * FM * 16;
    constexpr int BN = 2 * FN * 16;
    constexpr int CTS = BM + 4;
    __shared__ __align__(16) unsigned short sm[2 * BM * 64 + 2 * BN * 64];
    unsigned short* As0 = sm;
    unsigned short* As1 = sm + BM * 64;
    unsigned short* Bs0 = sm + 2 * BM * 64;
    unsigned short* Bs1 = sm + 2 * BM * 64 + BN * 64;
    const int lane = tid & 63, wave = tid >> 6;
    const int wm = (wave >> 1) * (FM * 16), wn = (wave & 1) * (FN * 16);
    const int l15 = lane & 15, lg = lane >> 4;

    f32x4 acc[FM][FN] = {};

    auto stage = [&](int buf, int k0) {
        unsigned short* as = buf ? As1 : As0;
        unsigned short* bs = buf ? Bs1 : Bs0;
#pragma unroll
        for (int q = 0; q < FM; ++q) {
            const int s = q * 256 + tid;
            GLD_LDS16(A + (size_t)(bm + (s >> 3)) * Kd + k0 + (s & 7) * 8,
                      &as[s * 8]);
        }
#pragma unroll
        for (int q = 0; q < FN; ++q) {
            const int s = q * 256 + tid;
            GLD_LDS16(Bt + (size_t)(bn + (s >> 3)) * Kd + k0 + (s & 7) * 8,
                      &bs[s * 8]);
        }
    };

    stage(0, 0);
    __syncthreads();
    int cur = 0;
    const int nt = Kd / 64;
    for (int t = 0; t < nt; ++t) {
        if (t + 1 < nt) stage(cur ^ 1, (t + 1) * 64);
        const unsigned short* as = cur ? As1 : As0;
        const unsigned short* bs = cur ? Bs1 : Bs0;
#pragma unroll
        for (int ks = 0; ks < 2; ++ks) {
            const int kb = ks * 32 + lg * 8;
            bf16x8 a[FM], b[FN];
#pragma unroll
            for (int f = 0; f < FM; ++f)
                a[f] = *reinterpret_cast<const bf16x8*>(&as[(wm + f * 16 + l15) * 64 + kb]);
#pragma unroll
            for (int f = 0; f < FN; ++f)
                b[f] = *reinterpret_cast<const bf16x8*>(&bs[(wn + f * 16 + l15) * 64 + kb]);
#pragma unroll
            for (int fm = 0; fm < FM; ++fm)
#pragma unroll
                for (int fn = 0; fn < FN; ++fn)
                    acc[fm][fn] = __builtin_amdgcn_mfma_f32_16x16x32_bf16(
                        a[fm], b[fn], acc[fm][fn], 0, 0, 0);
        }
        __syncthreads();
        cur ^= 1;
    }

#pragma unroll
    for (int fm = 0; fm < FM; ++fm)
#pragma unroll
        for (int fn = 0; fn < FN; ++fn) {
            const int cl = wn + fn * 16 + l15;
            const int col = bn + cl;
            const float bv = bias ? bias[col] : 0.f;
            const int rl = wm + fm * 16 + lg * 4;
            const int r0 = bm + rl;
            f32x4 v = acc[fm][fn];
            v[0] += bv; v[1] += bv; v[2] += bv; v[3] += bv;
            if (mode & 1) {
#pragma unroll
                for (int j = 0; j < 4; ++j)
                    cbf[(size_t)(r0 + j) * D_ + col] = f2bf(v[j]);
            }
            if (mode & 2) {
                *reinterpret_cast<ushort4*>(&sm[cl * CTS + rl]) = pack4(v);
            }
        }

    if (mode & 2) {
        __syncthreads();
        const int bI = bm >> 10, l0 = bm & 1023;
#pragma unroll
        for (int q = 0; q < BN * BM / 8 / 256; ++q) {
            const int slot = q * 256 + tid;
            const int cl = slot / (BM / 8), seg = slot % (BM / 8);
            const int gcol = bn + cl;
            const int h = gcol >> 6, n = gcol & 63;
            *reinterpret_cast<u16x8*>(
                ct + (((size_t)bI * NH_ + h) * 64 + n) * (size_t)L_ + l0 + seg * 8) =
                *reinterpret_cast<const u16x8*>(&sm[cl * CTS + seg * 8]);
        }
    }
}

// 5 x-projections; z selects output format.
__global__ __launch_bounds__(256) void k_gemm5(const unsigned short* __restrict__ A,
                                               const unsigned short* __restrict__ wt,
                                               const float* __restrict__ bq,
                                               const float* __restrict__ bk,
                                               const float* __restrict__ bv,
                                               const float* __restrict__ bg,
                                               unsigned short* __restrict__ ubf,
                                               unsigned short* __restrict__ qbf,
                                               unsigned short* __restrict__ ktb,
                                               unsigned short* __restrict__ vbf,
                                               unsigned short* __restrict__ vtb,
                                               unsigned short* __restrict__ gbf) {
    const int z = blockIdx.z;
    const float* bias = nullptr;
    int mode = 1;
    unsigned short* cbf = nullptr; unsigned short* ct = nullptr;
    switch (z) {
        case 0: mode = 1; cbf = ubf; bias = nullptr; break;
        case 1: mode = 1; cbf = qbf; bias = bq; break;
        case 2: mode = 2; ct = ktb; bias = bk; break;
        case 3: mode = 3; cbf = vbf; ct = vtb; bias = bv; break;
        default: mode = 1; cbf = gbf; bias = bg; break;
    }
    gemm_core<4, 4>(A, wt + (size_t)z * D_ * D_, bias, mode, cbf, ct,
                    D_, blockIdx.y * 128, blockIdx.x * 128, threadIdx.x);
}

// ---------------------------------------------------------------------------
// k_attnconv (384 threads):
//   blocks [0,384): chunked MFMA attention -> yab (bf16, pre-gate); waves 0-3
//     do the work (tid<256, wave-uniform guard), waves 4-5 idle through the
//     barriers.
//   blocks [384,640): parity conv -> xtb (bf16, no gate); all 384 threads,
//     4-way n-split x 96 r8-channels (max 128 serial steps/group).
// ---------------------------------------------------------------------------
__global__ __launch_bounds__(384) void k_attnconv(const unsigned short* __restrict__ qbf,
                                                  const unsigned short* __restrict__ vbf,
                                                  const unsigned short* __restrict__ ktb,
                                                  const unsigned short* __restrict__ vtb,
                                                  unsigned short* __restrict__ yab,
                                                  const unsigned short* __restrict__ ubf,
                                                  const unsigned short* __restrict__ phiev,
                                                  unsigned short* __restrict__ xtb) {
    __shared__ __align__(16) char smem_raw[75776];
    unsigned short* sm16 = (unsigned short*)smem_raw;
    const int tid = threadIdx.x;

    if (blockIdx.x >= 384) {
        // ---------------- conv part (all 384 threads) ----------------
        const int cu = (int)blockIdx.x - 384;      // 0..255
        const int m0 = (cu & 63) * 8;
        const int bp = cu >> 6;
        const int b = bp >> 1, p = bp & 1;
        u16x8* red = (u16x8*)sm16;                 // [4][8][96] = 49152 B

        const int g = tid / 96, lr = tid % 96;     // g in 0..3
        const int r = lr * 8;
        f32x8 acc[8] = {};
        f32x8 w[8] = {};
        const int ns = g * 128;
        const int ne = min(ns + 128, m0 + 8);
        if (ns < ne) {
            if (g > 0) {
#pragma unroll
                for (int j = 1; j <= 7; ++j)
                    w[(8 - j) & 7] = bf2f8(*reinterpret_cast<const u16x8*>(
                        phiev + (size_t)(ns - j) * R_ + r));
            }
            const unsigned short* pp = phiev + (size_t)ns * R_ + r;
            const unsigned short* up =
                ubf + ((size_t)(b * L_) + (size_t)(2 * (m0 + 7 - ns) + p)) * R_ + r;
            for (int i = ns; i < ne; i += 8) {
#pragma unroll
                for (int k = 0; k < 8; ++k) {
                    const u16x8 pv = *reinterpret_cast<const u16x8*>(pp);
                    const u16x8 uv = *reinterpret_cast<const u16x8*>(up);
                    w[k] = bf2f8(pv);
                    const f32x8 fu = bf2f8(uv);
#pragma unroll
                    for (int a = 0; a < 8; ++a)
                        acc[a] += w[(k + a + 1) & 7] * fu;
                    pp += R_;
                    up -= 2 * R_;
                }
            }
        }
#pragma unroll
        for (int a = 0; a < 8; ++a) red[(g * 8 + a) * 96 + lr] = pack8(acc[a]);
        __syncthreads();

#pragma unroll
        for (int q = 0; q < 2; ++q) {
            const int slot = q * 384 + tid;        // 768 = 8 a x 96 l
            const int a2 = slot / 96, l2 = slot % 96;
            f32x8 s = bf2f8(red[(0 * 8 + a2) * 96 + l2]) +
                      bf2f8(red[(1 * 8 + a2) * 96 + l2]) +
                      bf2f8(red[(2 * 8 + a2) * 96 + l2]) +
                      bf2f8(red[(3 * 8 + a2) * 96 + l2]);
            const size_t idx =
                ((size_t)(b * L_) + (size_t)(2 * (m0 + a2) + p)) * R_ + l2 * 8;
            *reinterpret_cast<u16x8*>(xtb + idx) = pack8(s);
        }
        return;
    }

    // ---------------- attn part (waves 0-3 compute) ----------------
    const int c = blockIdx.x & 15, h = (blockIdx.x >> 4) % NH_, b = blockIdx.x / (16 * NH_);
    unsigned short* Qs  = sm16;
    unsigned short* Vs  = sm16 + 4096;
    unsigned short* Kc  = sm16 + 8192;
    unsigned short* Tk0 = sm16 + 12288;
    unsigned short* Tk1 = sm16 + 16384;
    unsigned short* Tv0 = sm16 + 20480;
    unsigned short* Tv1 = sm16 + 24576;
    unsigned short* Sl  = sm16 + 28672;
    unsigned short* Hl  = sm16 + 33280;

    const bool aw = (tid < 256);                   // wave-uniform
    const int lane = tid & 63, wave = tid >> 6;
    const int wr = ((wave & 3) >> 1) * 32, wc = (wave & 1) * 32;
    const int l15 = lane & 15, lg = lane >> 4;

    if (aw) {
        const size_t rowbase = ((size_t)(b * L_ + c * CS_)) * D_ + h * HD_;
        const size_t tbase = ((size_t)(b * NH_ + h)) * 64 * (size_t)L_ + c * 64;
#pragma unroll
        for (int q2 = 0; q2 < 2; ++q2) {
            const int s = q2 * 256 + tid;
            const int row = s >> 3, c8 = s & 7;
            GLD_LDS16(qbf + rowbase + (size_t)row * D_ + c8 * 8, &Qs[s * 8]);
            GLD_LDS16(vbf + rowbase + (size_t)row * D_ + c8 * 8, &Vs[s * 8]);
            GLD_LDS16(ktb + tbase + (size_t)row * L_ + c8 * 8, &Kc[s * 8]);
        }
    }

    auto stage_t = [&](int buf, int cc) {
        if (!aw) return;
        unsigned short* tk = buf ? Tk1 : Tk0;
        unsigned short* tv = buf ? Tv1 : Tv0;
        const size_t tb2 = ((size_t)(b * NH_ + h)) * 64 * (size_t)L_ + cc * 64;
#pragma unroll
        for (int q2 = 0; q2 < 2; ++q2) {
            const int s = q2 * 256 + tid;
            const int row = s >> 3, c8 = s & 7;
            GLD_LDS16(ktb + tb2 + (size_t)row * L_ + c8 * 8, &tk[s * 8]);
            GLD_LDS16(vtb + tb2 + (size_t)row * L_ + c8 * 8, &tv[s * 8]);
        }
    };

    if (c > 0) stage_t(0, 0);
    __syncthreads();

    f32x4 hacc[2][2] = {};
    int cur = 0;
    for (int cc = 0; cc < c; ++cc) {
        if (cc + 1 < c) stage_t(cur ^ 1, cc + 1);
        if (aw) {
            const unsigned short* tk = cur ? Tk1 : Tk0;
            const unsigned short* tv = cur ? Tv1 : Tv0;
#pragma unroll
            for (int ks = 0; ks < 2; ++ks) {
                const int kb = ks * 32 + lg * 8;
                bf16x8 av[2], bk[2];
#pragma unroll
                for (int f = 0; f < 2; ++f) {
                    av[f] = *reinterpret_cast<const bf16x8*>(&tv[(wr + f * 16 + l15) * 64 + kb]);
                    bk[f] = *reinterpret_cast<const bf16x8*>(&tk[(wc + f * 16 + l15) * 64 + kb]);
                }
#pragma unroll
                for (int fm = 0; fm < 2; ++fm)
#pragma unroll
                    for (int fn = 0; fn < 2; ++fn)
                        hacc[fm][fn] = __builtin_amdgcn_mfma_f32_16x16x32_bf16(
                            av[fm], bk[fn], hacc[fm][fn], 0, 0, 0);
            }
        }
        __syncthreads();
        cur ^= 1;
    }

    if (aw && c > 0) {
#pragma unroll
        for (int fm = 0; fm < 2; ++fm)
#pragma unroll
            for (int fn = 0; fn < 2; ++fn) {
                const int n = wc + fn * 16 + l15;
                const int p0 = wr + fm * 16 + lg * 4;
                *reinterpret_cast<ushort4*>(&Hl[n * 72 + p0]) = pack4(hacc[fm][fn]);
            }
    }

    if (aw) {
        f32x4 sacc[2][2] = {};
#pragma unroll
        for (int ks = 0; ks < 2; ++ks) {
            const int kb = ks * 32 + lg * 8;
            bf16x8 av[2], bq[2];
#pragma unroll
            for (int f = 0; f < 2; ++f) {
                av[f] = *reinterpret_cast<const bf16x8*>(&Vs[(wr + f * 16 + l15) * 64 + kb]);
                bq[f] = *reinterpret_cast<const bf16x8*>(&Qs[(wc + f * 16 + l15) * 64 + kb]);
            }
#pragma unroll
            for (int fm = 0; fm < 2; ++fm)
#pragma unroll
                for (int fn = 0; fn < 2; ++fn)
                    sacc[fm][fn] = __builtin_amdgcn_mfma_f32_16x16x32_bf16(
                        av[fm], bq[fn], sacc[fm][fn], 0, 0, 0);
        }
#pragma unroll
        for (int fm = 0; fm < 2; ++fm)
#pragma unroll
            for (int fn = 0; fn < 2; ++fn) {
                const int t = wc + fn * 16 + l15;
                const int s0 = wr + fm * 16 + lg * 4;
#pragma unroll
                for (int j = 0; j < 4; ++j)
                    if (s0 + j > t) sacc[fm][fn][j] = 0.f;
                *reinterpret_cast<ushort4*>(&Sl[t * 72 + s0]) = pack4(sacc[fm][fn]);
            }
    }
    __syncthreads();

    if (aw) {
        f32x4 yacc[2][2] = {};
#pragma unroll
        for (int ks = 0; ks < 2; ++ks) {
            const int kb = ks * 32 + lg * 8;
            bf16x8 ak[2], bs[2];
#pragma unroll
            for (int f = 0; f < 2; ++f) {
                ak[f] = *reinterpret_cast<const bf16x8*>(&Kc[(wr + f * 16 + l15) * 64 + kb]);
                bs[f] = *reinterpret_cast<const bf16x8*>(&Sl[(wc + f * 16 + l15) * 72 + kb]);
            }
#pragma unroll
            for (int fm = 0; fm < 2; ++fm)
#pragma unroll
                for (int fn = 0; fn < 2; ++fn)
                    yacc[fm][fn] = __builtin_amdgcn_mfma_f32_16x16x32_bf16(
                        ak[fm], bs[fn], yacc[fm][fn], 0, 0, 0);
        }
        if (c > 0) {
#pragma unroll
            for (int ks = 0; ks < 2; ++ks) {
                const int kb = ks * 32 + lg * 8;
                bf16x8 ah[2], bq[2];
#pragma unroll
                for (int f = 0; f < 2; ++f) {
                    ah[f] = *reinterpret_cast<const bf16x8*>(&Hl[(wr + f * 16 + l15) * 72 + kb]);
                    bq[f] = *reinterpret_cast<const bf16x8*>(&Qs[(wc + f * 16 + l15) * 64 + kb]);
                }
#pragma unroll
                for (int fm = 0; fm < 2; ++fm)
#pragma unroll
                    for (int fn = 0; fn < 2; ++fn)
                        yacc[fm][fn] = __builtin_amdgcn_mfma_f32_16x16x32_bf16(
                            ah[fm], bq[fn], yacc[fm][fn], 0, 0, 0);
            }
        }

#pragma unroll
        for (int fm = 0; fm < 2; ++fm)
#pragma unroll
            for (int fn = 0; fn < 2; ++fn) {
                const int n0 = wr + fm * 16 + lg * 4;
                const int t = wc + fn * 16 + l15;
                const size_t idx = ((size_t)(b * L_ + c * CS_ + t)) * D_ + h * HD_ + n0;
                *reinterpret_cast<ushort4*>(yab + idx) = pack4(yacc[fm][fn]);
            }
    }
}

// ---------------------------------------------------------------------------
// k_outgemm: out = gate(xt, ya, g) @ Wo^T + bo,  gate fused in A-staging.
// BM=32, BN=64 (<1,2>), dbuf; A reg-staged: a = bf16(xt + (ya-xt)*sigmoid(g)).
// ---------------------------------------------------------------------------
__global__ __launch_bounds__(256) void k_outgemm(const unsigned short* __restrict__ xtb,
                                                 const unsigned short* __restrict__ yab,
                                                 const unsigned short* __restrict__ gbf,
                                                 const unsigned short* __restrict__ Bt,
                                                 const float* __restrict__ bias,
                                                 float* __restrict__ C) {
    constexpr int BM = 32, BN = 64;
    __shared__ __align__(16) unsigned short sm[2 * BM * 64 + 2 * BN * 64];
    unsigned short* As0 = sm;
    unsigned short* As1 = sm + BM * 64;
    unsigned short* Bs0 = sm + 2 * BM * 64;
    unsigned short* Bs1 = sm + 2 * BM * 64 + BN * 64;
    const int tid = threadIdx.x;
    const int bm = blockIdx.y * BM, bn = blockIdx.x * BN;
    const int lane = tid & 63, wave = tid >> 6;
    const int wm = (wave >> 1) * 16, wn = (wave & 1) * 32;
    const int l15 = lane & 15, lg = lane >> 4;

    f32x4 acc[1][2] = {};

    auto stage = [&](int buf, int k0) {
        {
            unsigned short* as = buf ? As1 : As0;
            const int row = tid >> 3, c8 = tid & 7;
            const size_t idx = (size_t)(bm + row) * D_ + k0 + c8 * 8;
            const f32x8 xv = bf2f8(*reinterpret_cast<const u16x8*>(xtb + idx));
            const f32x8 yv = bf2f8(*reinterpret_cast<const u16x8*>(yab + idx));
            const f32x8 gv = bf2f8(*reinterpret_cast<const u16x8*>(gbf + idx));
            f32x8 o;
#pragma unroll
            for (int e = 0; e < 8; ++e) {
                const float sg = 1.f / (1.f + expf(-gv[e]));
                o[e] = xv[e] + (yv[e] - xv[e]) * sg;
            }
            *reinterpret_cast<u16x8*>(&as[tid * 8]) = pack8(o);
        }
        {
            unsigned short* bs = buf ? Bs1 : Bs0;
#pragma unroll
            for (int q = 0; q < 2; ++q) {
                const int s = q * 256 + tid;
                GLD_LDS16(Bt + (size_t)(bn + (s >> 3)) * D_ + k0 + (s & 7) * 8,
                          &bs[s * 8]);
            }
        }
    };

    stage(0, 0);
    __syncthreads();
    int cur = 0;
    const int nt = D_ / 64;
    for (int t = 0; t < nt; ++t) {
        if (t + 1 < nt) stage(cur ^ 1, (t + 1) * 64);
        const unsigned short* as = cur ? As1 : As0;
        const unsigned short* bs = cur ? Bs1 : Bs0;
#pragma unroll
        for (int ks = 0; ks < 2; ++ks) {
            const int kb = ks * 32 + lg * 8;
            bf16x8 a0 = *reinterpret_cast<const bf16x8*>(&as[(wm + l15) * 64 + kb]);
            bf16x8 b0 = *reinterpret_cast<const bf16x8*>(&bs[(wn + l15) * 64 + kb]);
            bf16x8 b1 = *reinterpret_cast<const bf16x8*>(&bs[(wn + 16 + l15) * 64 + kb]);
            acc[0][0] = __builtin_amdgcn_mfma_f32_16x16x32_bf16(a0, b0, acc[0][0], 0, 0, 0);
            acc[0][1] = __builtin_amdgcn_mfma_f32_16x16x32_bf16(a0, b1, acc[0][1], 0, 0, 0);
        }
        __syncthreads();
        cur ^= 1;
    }

#pragma unroll
    for (int fn = 0; fn < 2; ++fn) {
        const int col = bn + wn + fn * 16 + l15;
        const float bv = bias[col];
        const int r0 = bm + wm + lg * 4;
#pragma unroll
        for (int j = 0; j < 4; ++j)
            C[(size_t)(r0 + j) * D_ + col] = acc[0][fn][j] + bv;
    }
}

// ---------------------------------------------------------------------------
extern "C" void kernel_launch(void* const* d_in, const int* in_sizes, int n_in,
                              void* d_out, int out_size, void* d_ws, size_t ws_size,
                              hipStream_t stream) {
    const float* x    = (const float*)d_in[0];
    const float* stu  = (const float*)d_in[1];
    const float* Mi   = (const float*)d_in[2];
    const float* Mf   = (const float*)d_in[3];
    const float* wq_w = (const float*)d_in[4];
    const float* wq_b = (const float*)d_in[5];
    const float* wk_w = (const float*)d_in[6];
    const float* wk_b = (const float*)d_in[7];
    const float* wv_w = (const float*)d_in[8];
    const float* wv_b = (const float*)d_in[9];
    const float* wg_w = (const float*)d_in[10];
    const float* wg_b = (const float*)d_in[11];
    const float* wo_w = (const float*)d_in[12];
    const float* wo_b = (const float*)d_in[13];
    float* out = (float*)d_out;

    char* ws = (char*)d_ws;
    size_t o = 0;
    const size_t WSZ = (size_t)D_ * D_;
    unsigned short* wbf   = (unsigned short*)(ws + o); o += 6 * WSZ * 2;
    unsigned short* xbf   = (unsigned short*)(ws + o); o += (size_t)B_ * L_ * D_ * 2;
    unsigned short* qbf   = (unsigned short*)(ws + o); o += (size_t)B_ * L_ * D_ * 2;
    unsigned short* vbf   = (unsigned short*)(ws + o); o += (size_t)B_ * L_ * D_ * 2;
    unsigned short* ubf   = (unsigned short*)(ws + o); o += (size_t)B_ * L_ * D_ * 2;
    unsigned short* gbf   = (unsigned short*)(ws + o); o += (size_t)B_ * L_ * D_ * 2;
    unsigned short* yab   = (unsigned short*)(ws + o); o += (size_t)B_ * L_ * D_ * 2;
    unsigned short* xtb   = (unsigned short*)(ws + o); o += (size_t)B_ * L_ * D_ * 2;
    unsigned short* ktb   = (unsigned short*)(ws + o); o += (size_t)B_ * NH_ * 64 * L_ * 2;
    unsigned short* vtb   = (unsigned short*)(ws + o); o += (size_t)B_ * NH_ * 64 * L_ * 2;
    unsigned short* phiev = (unsigned short*)(ws + o); o += (size_t)(L_ / 2) * R_ * 2;

    unsigned short* wo_t = wbf + 5 * WSZ;

    const dim3 blk(256);

    k_prep<<<dim3(3168), blk, 0, stream>>>(Mi, wq_w, wk_w, wv_w, wg_w, wo_w, wbf,
                                           x, xbf, stu, Mf, phiev);

    k_gemm5<<<dim3(D_ / 128, (B_ * L_) / 128, 5), blk, 0, stream>>>(
        xbf, wbf, wq_b, wk_b, wv_b, wg_b, ubf, qbf, ktb, vbf, vtb, gbf);

    k_attnconv<<<dim3(640), dim3(384), 0, stream>>>(qbf, vbf, ktb, vtb, yab,
                                                    ubf, phiev, xtb);

    k_outgemm<<<dim3(D_ / 64, (B_ * L_) / 32), blk, 0, stream>>>(
        xtb, yab, gbf, wo_t, wo_b, out);
}

// Round 17
// 107.938 us; speedup vs baseline: 1.0910x; 1.0910x over previous
//
#include <hip/hip_runtime.h>
#include <math.h>

#define B_  2
#define L_  1024
#define D_  768
#define NH_ 12
#define HD_ 64
#define K_  24
#define R_  768
#define NC_ 16
#define CS_ 64

typedef __bf16 bf16x8 __attribute__((ext_vector_type(8)));
typedef float f32x4 __attribute__((ext_vector_type(4)));
typedef float f32x8 __attribute__((ext_vector_type(8)));
typedef unsigned short u16x8 __attribute__((ext_vector_type(8)));

__device__ inline unsigned short f2bf(float f) {
    union { float f; unsigned u; } v; v.f = f;
    unsigned r = v.u + 0x7FFFu + ((v.u >> 16) & 1u);
    return (unsigned short)(r >> 16);
}

__device__ inline ushort4 pack4(const f32x4 v) {
    ushort4 r;
    r.x = f2bf(v[0]); r.y = f2bf(v[1]); r.z = f2bf(v[2]); r.w = f2bf(v[3]);
    return r;
}

__device__ inline u16x8 pack8(const f32x8 v) {
    u16x8 r;
#pragma unroll
    for (int e = 0; e < 8; ++e) r[e] = f2bf(v[e]);
    return r;
}

__device__ inline f32x8 bf2f8(const u16x8 v) {
    f32x8 r;
#pragma unroll
    for (int e = 0; e < 8; ++e) {
        union { float f; unsigned u; } t;
        t.u = ((unsigned)v[e]) << 16;
        r[e] = t.f;
    }
    return r;
}

#define GLD_LDS16(g, l)                                                     \
    __builtin_amdgcn_global_load_lds(                                       \
        (const __attribute__((address_space(1))) void*)(g),                 \
        (__attribute__((address_space(3))) void*)(l), 16, 0, 0)

// ---------------------------------------------------------------------------
// k_prep: [0,864) weight transposes; [864,1632) x->bf16; [1632,3168) phiev
// ---------------------------------------------------------------------------
__global__ __launch_bounds__(256) void k_prep(const float* __restrict__ w0,
                                              const float* __restrict__ w1,
                                              const float* __restrict__ w2,
                                              const float* __restrict__ w3,
                                              const float* __restrict__ w4,
                                              const float* __restrict__ w5,
                                              unsigned short* __restrict__ Wt,
                                              const float* __restrict__ x,
                                              unsigned short* __restrict__ xb,
                                              const float* __restrict__ F,
                                              const float* __restrict__ Mf,
                                              unsigned short* __restrict__ phiev) {
    const int bid = blockIdx.x;
    const int tid = threadIdx.x;
    if (bid < 864) {
        const int z = bid / 144, rem = bid % 144;
        const float* W;
        switch (z) {
            case 0: W = w0; break;
            case 1: W = w1; break;
            case 2: W = w2; break;
            case 3: W = w3; break;
            case 4: W = w4; break;
            default: W = w5; break;
        }
        unsigned short* o = Wt + (size_t)z * D_ * D_;
        __shared__ float t[64][69];
        const int n0 = (rem % 12) * 64, k0 = (rem / 12) * 64;
        const int row = tid >> 4, c4 = (tid & 15) * 4;
#pragma unroll
        for (int i = 0; i < 4; ++i) {
            const float4 v = *reinterpret_cast<const float4*>(
                W + (size_t)(k0 + row + i * 16) * D_ + n0 + c4);
            t[row + i * 16][c4 + 0] = v.x;
            t[row + i * 16][c4 + 1] = v.y;
            t[row + i * 16][c4 + 2] = v.z;
            t[row + i * 16][c4 + 3] = v.w;
        }
        __syncthreads();
#pragma unroll
        for (int i = 0; i < 4; ++i) {
            const int nn = row + i * 16;
            ushort4 o4;
            o4.x = f2bf(t[c4 + 0][nn]);
            o4.y = f2bf(t[c4 + 1][nn]);
            o4.z = f2bf(t[c4 + 2][nn]);
            o4.w = f2bf(t[c4 + 3][nn]);
            *reinterpret_cast<ushort4*>(o + (size_t)(n0 + nn) * D_ + k0 + c4) = o4;
        }
    } else if (bid < 1632) {
        const int i8 = ((bid - 864) * 256 + tid) * 8;
        float4 f0 = *reinterpret_cast<const float4*>(x + i8);
        float4 f1 = *reinterpret_cast<const float4*>(x + i8 + 4);
        u16x8 p;
        p[0] = f2bf(f0.x); p[1] = f2bf(f0.y); p[2] = f2bf(f0.z); p[3] = f2bf(f0.w);
        p[4] = f2bf(f1.x); p[5] = f2bf(f1.y); p[6] = f2bf(f1.z); p[7] = f2bf(f1.w);
        *reinterpret_cast<u16x8*>(xb + i8) = p;
    } else {
        const int idx = (bid - 1632) * 256 + tid;    // over 512*768
        const int r = idx % R_;
        const int n = idx / R_;
        float acc = 0.f;
#pragma unroll
        for (int kk = 0; kk < K_; ++kk)
            acc += F[(2 * n) * K_ + kk] * Mf[kk * R_ + r];
        phiev[idx] = f2bf(2.f * acc);
    }
}

// ---------------------------------------------------------------------------
// bf16 MFMA GEMM core, 2-phase dbuf; mode 1 bf16 row, 2 transposed, 3 both.
// ---------------------------------------------------------------------------
template <int FM, int FN>
__device__ __forceinline__ void gemm_core(const unsigned short* __restrict__ A,
                                          const unsigned short* __restrict__ Bt,
                                          const float* __restrict__ bias,
                                          int mode,
                                          unsigned short* __restrict__ cbf,
                                          unsigned short* __restrict__ ct,
                                          int Kd, int bm, int bn, int tid) {
    constexpr int BM = 2 * FM * 16;
    constexpr int BN = 2 * FN * 16;
    constexpr int CTS = BM + 4;
    __shared__ __align__(16) unsigned short sm[2 * BM * 64 + 2 * BN * 64];
    unsigned short* As0 = sm;
    unsigned short* As1 = sm + BM * 64;
    unsigned short* Bs0 = sm + 2 * BM * 64;
    unsigned short* Bs1 = sm + 2 * BM * 64 + BN * 64;
    const int lane = tid & 63, wave = tid >> 6;
    const int wm = (wave >> 1) * (FM * 16), wn = (wave & 1) * (FN * 16);
    const int l15 = lane & 15, lg = lane >> 4;

    f32x4 acc[FM][FN] = {};

    auto stage = [&](int buf, int k0) {
        unsigned short* as = buf ? As1 : As0;
        unsigned short* bs = buf ? Bs1 : Bs0;
#pragma unroll
        for (int q = 0; q < FM; ++q) {
            const int s = q * 256 + tid;
            GLD_LDS16(A + (size_t)(bm + (s >> 3)) * Kd + k0 + (s & 7) * 8,
                      &as[s * 8]);
        }
#pragma unroll
        for (int q = 0; q < FN; ++q) {
            const int s = q * 256 + tid;
            GLD_LDS16(Bt + (size_t)(bn + (s >> 3)) * Kd + k0 + (s & 7) * 8,
                      &bs[s * 8]);
        }
    };

    stage(0, 0);
    __syncthreads();
    int cur = 0;
    const int nt = Kd / 64;
    for (int t = 0; t < nt; ++t) {
        if (t + 1 < nt) stage(cur ^ 1, (t + 1) * 64);
        const unsigned short* as = cur ? As1 : As0;
        const unsigned short* bs = cur ? Bs1 : Bs0;
#pragma unroll
        for (int ks = 0; ks < 2; ++ks) {
            const int kb = ks * 32 + lg * 8;
            bf16x8 a[FM], b[FN];
#pragma unroll
            for (int f = 0; f < FM; ++f)
                a[f] = *reinterpret_cast<const bf16x8*>(&as[(wm + f * 16 + l15) * 64 + kb]);
#pragma unroll
            for (int f = 0; f < FN; ++f)
                b[f] = *reinterpret_cast<const bf16x8*>(&bs[(wn + f * 16 + l15) * 64 + kb]);
#pragma unroll
            for (int fm = 0; fm < FM; ++fm)
#pragma unroll
                for (int fn = 0; fn < FN; ++fn)
                    acc[fm][fn] = __builtin_amdgcn_mfma_f32_16x16x32_bf16(
                        a[fm], b[fn], acc[fm][fn], 0, 0, 0);
        }
        __syncthreads();
        cur ^= 1;
    }

#pragma unroll
    for (int fm = 0; fm < FM; ++fm)
#pragma unroll
        for (int fn = 0; fn < FN; ++fn) {
            const int cl = wn + fn * 16 + l15;
            const int col = bn + cl;
            const float bv = bias ? bias[col] : 0.f;
            const int rl = wm + fm * 16 + lg * 4;
            const int r0 = bm + rl;
            f32x4 v = acc[fm][fn];
            v[0] += bv; v[1] += bv; v[2] += bv; v[3] += bv;
            if (mode & 1) {
#pragma unroll
                for (int j = 0; j < 4; ++j)
                    cbf[(size_t)(r0 + j) * D_ + col] = f2bf(v[j]);
            }
            if (mode & 2) {
                *reinterpret_cast<ushort4*>(&sm[cl * CTS + rl]) = pack4(v);
            }
        }

    if (mode & 2) {
        __syncthreads();
        const int bI = bm >> 10, l0 = bm & 1023;
#pragma unroll
        for (int q = 0; q < BN * BM / 8 / 256; ++q) {
            const int slot = q * 256 + tid;
            const int cl = slot / (BM / 8), seg = slot % (BM / 8);
            const int gcol = bn + cl;
            const int h = gcol >> 6, n = gcol & 63;
            *reinterpret_cast<u16x8*>(
                ct + (((size_t)bI * NH_ + h) * 64 + n) * (size_t)L_ + l0 + seg * 8) =
                *reinterpret_cast<const u16x8*>(&sm[cl * CTS + seg * 8]);
        }
    }
}

// 5 x-projections; z selects output format.
__global__ __launch_bounds__(256) void k_gemm5(const unsigned short* __restrict__ A,
                                               const unsigned short* __restrict__ wt,
                                               const float* __restrict__ bq,
                                               const float* __restrict__ bk,
                                               const float* __restrict__ bv,
                                               const float* __restrict__ bg,
                                               unsigned short* __restrict__ ubf,
                                               unsigned short* __restrict__ qbf,
                                               unsigned short* __restrict__ ktb,
                                               unsigned short* __restrict__ vbf,
                                               unsigned short* __restrict__ vtb,
                                               unsigned short* __restrict__ gbf) {
    const int z = blockIdx.z;
    const float* bias = nullptr;
    int mode = 1;
    unsigned short* cbf = nullptr; unsigned short* ct = nullptr;
    switch (z) {
        case 0: mode = 1; cbf = ubf; bias = nullptr; break;
        case 1: mode = 1; cbf = qbf; bias = bq; break;
        case 2: mode = 2; ct = ktb; bias = bk; break;
        case 3: mode = 3; cbf = vbf; ct = vtb; bias = bv; break;
        default: mode = 1; cbf = gbf; bias = bg; break;
    }
    gemm_core<4, 4>(A, wt + (size_t)z * D_ * D_, bias, mode, cbf, ct,
                    D_, blockIdx.y * 128, blockIdx.x * 128, threadIdx.x);
}

// ---------------------------------------------------------------------------
// k_attn: chunked MFMA attention -> yab (bf16, pre-gate). 384 blocks (c,h,b).
// ---------------------------------------------------------------------------
__global__ __launch_bounds__(256) void k_attn(const unsigned short* __restrict__ qbf,
                                              const unsigned short* __restrict__ vbf,
                                              const unsigned short* __restrict__ ktb,
                                              const unsigned short* __restrict__ vtb,
                                              unsigned short* __restrict__ yab) {
    const int c = blockIdx.x & 15, h = (blockIdx.x >> 4) % NH_, b = blockIdx.x / (16 * NH_);
    __shared__ unsigned short Qs[64 * 64];
    __shared__ unsigned short Vs[64 * 64];
    __shared__ unsigned short Kc[64 * 64];
    __shared__ unsigned short Tk[2][64 * 64];
    __shared__ unsigned short Tv[2][64 * 64];
    __shared__ unsigned short Sl[64 * 72];
    __shared__ unsigned short Hl[64 * 72];

    const int tid = threadIdx.x;
    const int lane = tid & 63, wave = tid >> 6;
    const int wr = (wave >> 1) * 32, wc = (wave & 1) * 32;
    const int l15 = lane & 15, lg = lane >> 4;

    {
        const size_t rowbase = ((size_t)(b * L_ + c * CS_)) * D_ + h * HD_;
        const size_t tbase = ((size_t)(b * NH_ + h)) * 64 * (size_t)L_ + c * 64;
#pragma unroll
        for (int q2 = 0; q2 < 2; ++q2) {
            const int s = q2 * 256 + tid;
            const int row = s >> 3, c8 = s & 7;
            GLD_LDS16(qbf + rowbase + (size_t)row * D_ + c8 * 8, &Qs[s * 8]);
            GLD_LDS16(vbf + rowbase + (size_t)row * D_ + c8 * 8, &Vs[s * 8]);
            GLD_LDS16(ktb + tbase + (size_t)row * L_ + c8 * 8, &Kc[s * 8]);
        }
    }

    auto stage_t = [&](int buf, int cc) {
        const size_t tb2 = ((size_t)(b * NH_ + h)) * 64 * (size_t)L_ + cc * 64;
#pragma unroll
        for (int q2 = 0; q2 < 2; ++q2) {
            const int s = q2 * 256 + tid;
            const int row = s >> 3, c8 = s & 7;
            GLD_LDS16(ktb + tb2 + (size_t)row * L_ + c8 * 8, &Tk[buf][s * 8]);
            GLD_LDS16(vtb + tb2 + (size_t)row * L_ + c8 * 8, &Tv[buf][s * 8]);
        }
    };

    if (c > 0) stage_t(0, 0);
    __syncthreads();

    f32x4 hacc[2][2] = {};
    int cur = 0;
    for (int cc = 0; cc < c; ++cc) {
        if (cc + 1 < c) stage_t(cur ^ 1, cc + 1);
#pragma unroll
        for (int ks = 0; ks < 2; ++ks) {
            const int kb = ks * 32 + lg * 8;
            bf16x8 av[2], bk[2];
#pragma unroll
            for (int f = 0; f < 2; ++f) {
                av[f] = *reinterpret_cast<const bf16x8*>(&Tv[cur][(wr + f * 16 + l15) * 64 + kb]);
                bk[f] = *reinterpret_cast<const bf16x8*>(&Tk[cur][(wc + f * 16 + l15) * 64 + kb]);
            }
#pragma unroll
            for (int fm = 0; fm < 2; ++fm)
#pragma unroll
                for (int fn = 0; fn < 2; ++fn)
                    hacc[fm][fn] = __builtin_amdgcn_mfma_f32_16x16x32_bf16(
                        av[fm], bk[fn], hacc[fm][fn], 0, 0, 0);
        }
        __syncthreads();
        cur ^= 1;
    }

    if (c > 0) {
#pragma unroll
        for (int fm = 0; fm < 2; ++fm)
#pragma unroll
            for (int fn = 0; fn < 2; ++fn) {
                const int n = wc + fn * 16 + l15;
                const int p0 = wr + fm * 16 + lg * 4;
                *reinterpret_cast<ushort4*>(&Hl[n * 72 + p0]) = pack4(hacc[fm][fn]);
            }
    }

    {
        f32x4 sacc[2][2] = {};
#pragma unroll
        for (int ks = 0; ks < 2; ++ks) {
            const int kb = ks * 32 + lg * 8;
            bf16x8 av[2], bq[2];
#pragma unroll
            for (int f = 0; f < 2; ++f) {
                av[f] = *reinterpret_cast<const bf16x8*>(&Vs[(wr + f * 16 + l15) * 64 + kb]);
                bq[f] = *reinterpret_cast<const bf16x8*>(&Qs[(wc + f * 16 + l15) * 64 + kb]);
            }
#pragma unroll
            for (int fm = 0; fm < 2; ++fm)
#pragma unroll
                for (int fn = 0; fn < 2; ++fn)
                    sacc[fm][fn] = __builtin_amdgcn_mfma_f32_16x16x32_bf16(
                        av[fm], bq[fn], sacc[fm][fn], 0, 0, 0);
        }
#pragma unroll
        for (int fm = 0; fm < 2; ++fm)
#pragma unroll
            for (int fn = 0; fn < 2; ++fn) {
                const int t = wc + fn * 16 + l15;
                const int s0 = wr + fm * 16 + lg * 4;
#pragma unroll
                for (int j = 0; j < 4; ++j)
                    if (s0 + j > t) sacc[fm][fn][j] = 0.f;
                *reinterpret_cast<ushort4*>(&Sl[t * 72 + s0]) = pack4(sacc[fm][fn]);
            }
    }
    __syncthreads();

    f32x4 yacc[2][2] = {};
#pragma unroll
    for (int ks = 0; ks < 2; ++ks) {
        const int kb = ks * 32 + lg * 8;
        bf16x8 ak[2], bs[2];
#pragma unroll
        for (int f = 0; f < 2; ++f) {
            ak[f] = *reinterpret_cast<const bf16x8*>(&Kc[(wr + f * 16 + l15) * 64 + kb]);
            bs[f] = *reinterpret_cast<const bf16x8*>(&Sl[(wc + f * 16 + l15) * 72 + kb]);
        }
#pragma unroll
        for (int fm = 0; fm < 2; ++fm)
#pragma unroll
            for (int fn = 0; fn < 2; ++fn)
                yacc[fm][fn] = __builtin_amdgcn_mfma_f32_16x16x32_bf16(
                    ak[fm], bs[fn], yacc[fm][fn], 0, 0, 0);
    }
    if (c > 0) {
#pragma unroll
        for (int ks = 0; ks < 2; ++ks) {
            const int kb = ks * 32 + lg * 8;
            bf16x8 ah[2], bq[2];
#pragma unroll
            for (int f = 0; f < 2; ++f) {
                ah[f] = *reinterpret_cast<const bf16x8*>(&Hl[(wr + f * 16 + l15) * 72 + kb]);
                bq[f] = *reinterpret_cast<const bf16x8*>(&Qs[(wc + f * 16 + l15) * 64 + kb]);
            }
#pragma unroll
            for (int fm = 0; fm < 2; ++fm)
#pragma unroll
                for (int fn = 0; fn < 2; ++fn)
                    yacc[fm][fn] = __builtin_amdgcn_mfma_f32_16x16x32_bf16(
                        ah[fm], bq[fn], yacc[fm][fn], 0, 0, 0);
        }
    }

#pragma unroll
    for (int fm = 0; fm < 2; ++fm)
#pragma unroll
        for (int fn = 0; fn < 2; ++fn) {
            const int n0 = wr + fm * 16 + lg * 4;
            const int t = wc + fn * 16 + l15;
            const size_t idx = ((size_t)(b * L_ + c * CS_ + t)) * D_ + h * HD_ + n0;
            *reinterpret_cast<ushort4*>(yab + idx) = pack4(yacc[fm][fn]);
        }
}

// ---------------------------------------------------------------------------
// k_conv: load-balanced parity conv -> xtb (bf16, no gate).
// 256 blocks = pair(32) x bp(4) x rhalf(2); 384 thr = 8 stripe-groups x 48 r8.
// Block processes m-groups pi and 63-pi (65 stripes total, constant).
// Group g handles stripes s ≡ g (mod 8); each stripe: 7-elem window preload
// (slots (8-j)&7, compile-time) + 8 steps.
// ---------------------------------------------------------------------------
__global__ __launch_bounds__(384) void k_conv(const unsigned short* __restrict__ ubf,
                                              const unsigned short* __restrict__ phiev,
                                              unsigned short* __restrict__ xtb) {
    __shared__ u16x8 red[8][8][48];             // 49152 B
    const int tid = threadIdx.x;
    const int g  = tid / 48;                    // 0..7
    const int lr = tid % 48;
    const int bid = blockIdx.x;
    const int pr = bid & 1;                     // r-half
    const int bp = (bid >> 1) & 3;
    const int pi = bid >> 3;                    // pair 0..31
    const int b = bp >> 1, p = bp & 1;
    const int r = (pr * 48 + lr) * 8;

#pragma unroll
    for (int half = 0; half < 2; ++half) {
        const int mg = half ? (63 - pi) : pi;
        const int m0 = mg * 8;
        const int S  = mg + 1;                  // stripes
        f32x8 acc[8] = {};
        f32x8 w[8]   = {};

        for (int s = g; s < S; s += 8) {
            const int i0 = s * 8;
            if (s > 0) {
#pragma unroll
                for (int j = 1; j <= 7; ++j)
                    w[(8 - j) & 7] = bf2f8(*reinterpret_cast<const u16x8*>(
                        phiev + (size_t)(i0 - j) * R_ + r));
            }
            const unsigned short* pp = phiev + (size_t)i0 * R_ + r;
            const unsigned short* up =
                ubf + ((size_t)(b * L_) + (size_t)(2 * (m0 + 7 - i0) + p)) * R_ + r;
#pragma unroll
            for (int k = 0; k < 8; ++k) {
                const u16x8 pv = *reinterpret_cast<const u16x8*>(pp);
                const u16x8 uv = *reinterpret_cast<const u16x8*>(up);
                w[k] = bf2f8(pv);
                const f32x8 fu = bf2f8(uv);
#pragma unroll
                for (int a = 0; a < 8; ++a)
                    acc[a] += w[(k + a + 1) & 7] * fu;
                pp += R_;
                up -= 2 * R_;
            }
        }

#pragma unroll
        for (int a = 0; a < 8; ++a) red[g][a][lr] = pack8(acc[a]);
        __syncthreads();

        // 384 threads reduce 8x48 = 384 slots (one each)
        {
            const f32x8 sres = bf2f8(red[0][g][lr]) + bf2f8(red[1][g][lr]) +
                               bf2f8(red[2][g][lr]) + bf2f8(red[3][g][lr]) +
                               bf2f8(red[4][g][lr]) + bf2f8(red[5][g][lr]) +
                               bf2f8(red[6][g][lr]) + bf2f8(red[7][g][lr]);
            // slot (a2=g, l2=lr): wrong — need per-thread unique (a,l) slot.
            // map: a2 = g (0..7), l2 = lr (0..47): that's exactly 8x48 ✓
            const size_t idx =
                ((size_t)(b * L_) + (size_t)(2 * (m0 + g) + p)) * R_ + r;
            // NOTE: here a2 == g, reading red[*][g][lr] sums group-partials of
            // output row a=g, channel lr ✓
            *reinterpret_cast<u16x8*>(xtb + idx) = pack8(sres);
        }
        if (half == 0) __syncthreads();         // red reused next half
    }
}

// ---------------------------------------------------------------------------
// k_outgemm: out = gate(xt, ya, g) @ Wo^T + bo, gate fused in A-staging.
// ---------------------------------------------------------------------------
__global__ __launch_bounds__(256) void k_outgemm(const unsigned short* __restrict__ xtb,
                                                 const unsigned short* __restrict__ yab,
                                                 const unsigned short* __restrict__ gbf,
                                                 const unsigned short* __restrict__ Bt,
                                                 const float* __restrict__ bias,
                                                 float* __restrict__ C) {
    constexpr int BM = 32, BN = 64;
    __shared__ __align__(16) unsigned short sm[2 * BM * 64 + 2 * BN * 64];
    unsigned short* As0 = sm;
    unsigned short* As1 = sm + BM * 64;
    unsigned short* Bs0 = sm + 2 * BM * 64;
    unsigned short* Bs1 = sm + 2 * BM * 64 + BN * 64;
    const int tid = threadIdx.x;
    const int bm = blockIdx.y * BM, bn = blockIdx.x * BN;
    const int lane = tid & 63, wave = tid >> 6;
    const int wm = (wave >> 1) * 16, wn = (wave & 1) * 32;
    const int l15 = lane & 15, lg = lane >> 4;

    f32x4 acc[1][2] = {};

    auto stage = [&](int buf, int k0) {
        {
            unsigned short* as = buf ? As1 : As0;
            const int row = tid >> 3, c8 = tid & 7;
            const size_t idx = (size_t)(bm + row) * D_ + k0 + c8 * 8;
            const f32x8 xv = bf2f8(*reinterpret_cast<const u16x8*>(xtb + idx));
            const f32x8 yv = bf2f8(*reinterpret_cast<const u16x8*>(yab + idx));
            const f32x8 gv = bf2f8(*reinterpret_cast<const u16x8*>(gbf + idx));
            f32x8 o;
#pragma unroll
            for (int e = 0; e < 8; ++e) {
                const float sg = 1.f / (1.f + expf(-gv[e]));
                o[e] = xv[e] + (yv[e] - xv[e]) * sg;
            }
            *reinterpret_cast<u16x8*>(&as[tid * 8]) = pack8(o);
        }
        {
            unsigned short* bs = buf ? Bs1 : Bs0;
#pragma unroll
            for (int q = 0; q < 2; ++q) {
                const int s = q * 256 + tid;
                GLD_LDS16(Bt + (size_t)(bn + (s >> 3)) * D_ + k0 + (s & 7) * 8,
                          &bs[s * 8]);
            }
        }
    };

    stage(0, 0);
    __syncthreads();
    int cur = 0;
    const int nt = D_ / 64;
    for (int t = 0; t < nt; ++t) {
        if (t + 1 < nt) stage(cur ^ 1, (t + 1) * 64);
        const unsigned short* as = cur ? As1 : As0;
        const unsigned short* bs = cur ? Bs1 : Bs0;
#pragma unroll
        for (int ks = 0; ks < 2; ++ks) {
            const int kb = ks * 32 + lg * 8;
            bf16x8 a0 = *reinterpret_cast<const bf16x8*>(&as[(wm + l15) * 64 + kb]);
            bf16x8 b0 = *reinterpret_cast<const bf16x8*>(&bs[(wn + l15) * 64 + kb]);
            bf16x8 b1 = *reinterpret_cast<const bf16x8*>(&bs[(wn + 16 + l15) * 64 + kb]);
            acc[0][0] = __builtin_amdgcn_mfma_f32_16x16x32_bf16(a0, b0, acc[0][0], 0, 0, 0);
            acc[0][1] = __builtin_amdgcn_mfma_f32_16x16x32_bf16(a0, b1, acc[0][1], 0, 0, 0);
        }
        __syncthreads();
        cur ^= 1;
    }

#pragma unroll
    for (int fn = 0; fn < 2; ++fn) {
        const int col = bn + wn + fn * 16 + l15;
        const float bv = bias[col];
        const int r0 = bm + wm + lg * 4;
#pragma unroll
        for (int j = 0; j < 4; ++j)
            C[(size_t)(r0 + j) * D_ + col] = acc[0][fn][j] + bv;
    }
}

// ---------------------------------------------------------------------------
extern "C" void kernel_launch(void* const* d_in, const int* in_sizes, int n_in,
                              void* d_out, int out_size, void* d_ws, size_t ws_size,
                              hipStream_t stream) {
    const float* x    = (const float*)d_in[0];
    const float* stu  = (const float*)d_in[1];
    const float* Mi   = (const float*)d_in[2];
    const float* Mf   = (const float*)d_in[3];
    const float* wq_w = (const float*)d_in[4];
    const float* wq_b = (const float*)d_in[5];
    const float* wk_w = (const float*)d_in[6];
    const float* wk_b = (const float*)d_in[7];
    const float* wv_w = (const float*)d_in[8];
    const float* wv_b = (const float*)d_in[9];
    const float* wg_w = (const float*)d_in[10];
    const float* wg_b = (const float*)d_in[11];
    const float* wo_w = (const float*)d_in[12];
    const float* wo_b = (const float*)d_in[13];
    float* out = (float*)d_out;

    char* ws = (char*)d_ws;
    size_t o = 0;
    const size_t WSZ = (size_t)D_ * D_;
    unsigned short* wbf   = (unsigned short*)(ws + o); o += 6 * WSZ * 2;
    unsigned short* xbf   = (unsigned short*)(ws + o); o += (size_t)B_ * L_ * D_ * 2;
    unsigned short* qbf   = (unsigned short*)(ws + o); o += (size_t)B_ * L_ * D_ * 2;
    unsigned short* vbf   = (unsigned short*)(ws + o); o += (size_t)B_ * L_ * D_ * 2;
    unsigned short* ubf   = (unsigned short*)(ws + o); o += (size_t)B_ * L_ * D_ * 2;
    unsigned short* gbf   = (unsigned short*)(ws + o); o += (size_t)B_ * L_ * D_ * 2;
    unsigned short* yab   = (unsigned short*)(ws + o); o += (size_t)B_ * L_ * D_ * 2;
    unsigned short* xtb   = (unsigned short*)(ws + o); o += (size_t)B_ * L_ * D_ * 2;
    unsigned short* ktb   = (unsigned short*)(ws + o); o += (size_t)B_ * NH_ * 64 * L_ * 2;
    unsigned short* vtb   = (unsigned short*)(ws + o); o += (size_t)B_ * NH_ * 64 * L_ * 2;
    unsigned short* phiev = (unsigned short*)(ws + o); o += (size_t)(L_ / 2) * R_ * 2;

    unsigned short* wo_t = wbf + 5 * WSZ;

    const dim3 blk(256);

    k_prep<<<dim3(3168), blk, 0, stream>>>(Mi, wq_w, wk_w, wv_w, wg_w, wo_w, wbf,
                                           x, xbf, stu, Mf, phiev);

    k_gemm5<<<dim3(D_ / 128, (B_ * L_) / 128, 5), blk, 0, stream>>>(
        xbf, wbf, wq_b, wk_b, wv_b, wg_b, ubf, qbf, ktb, vbf, vtb, gbf);

    k_attn<<<dim3(384), blk, 0, stream>>>(qbf, vbf, ktb, vtb, yab);

    k_conv<<<dim3(256), dim3(384), 0, stream>>>(ubf, phiev, xtb);

    k_outgemm<<<dim3(D_ / 64, (B_ * L_) / 32), blk, 0, stream>>>(
        xtb, yab, gbf, wo_t, wo_b, out);
}

// Round 18
// 92.408 us; speedup vs baseline: 1.2743x; 1.1681x over previous
//
#include <hip/hip_runtime.h>
#include <math.h>

#define B_  2
#define L_  1024
#define D_  768
#define NH_ 12
#define HD_ 64
#define K_  24
#define R_  768
#define NC_ 16
#define CS_ 64

typedef __bf16 bf16x8 __attribute__((ext_vector_type(8)));
typedef float f32x4 __attribute__((ext_vector_type(4)));
typedef float f32x8 __attribute__((ext_vector_type(8)));
typedef unsigned short u16x8 __attribute__((ext_vector_type(8)));

__device__ inline unsigned short f2bf(float f) {
    union { float f; unsigned u; } v; v.f = f;
    unsigned r = v.u + 0x7FFFu + ((v.u >> 16) & 1u);
    return (unsigned short)(r >> 16);
}

__device__ inline ushort4 pack4(const f32x4 v) {
    ushort4 r;
    r.x = f2bf(v[0]); r.y = f2bf(v[1]); r.z = f2bf(v[2]); r.w = f2bf(v[3]);
    return r;
}

__device__ inline u16x8 pack8(const f32x8 v) {
    u16x8 r;
#pragma unroll
    for (int e = 0; e < 8; ++e) r[e] = f2bf(v[e]);
    return r;
}

__device__ inline f32x8 bf2f8(const u16x8 v) {
    f32x8 r;
#pragma unroll
    for (int e = 0; e < 8; ++e) {
        union { float f; unsigned u; } t;
        t.u = ((unsigned)v[e]) << 16;
        r[e] = t.f;
    }
    return r;
}

#define GLD_LDS16(g, l)                                                     \
    __builtin_amdgcn_global_load_lds(                                       \
        (const __attribute__((address_space(1))) void*)(g),                 \
        (__attribute__((address_space(3))) void*)(l), 16, 0, 0)

// ---------------------------------------------------------------------------
// k_prep: [0,864) weight transposes; [864,1632) x->bf16; [1632,3168) phiev
// ---------------------------------------------------------------------------
__global__ __launch_bounds__(256) void k_prep(const float* __restrict__ w0,
                                              const float* __restrict__ w1,
                                              const float* __restrict__ w2,
                                              const float* __restrict__ w3,
                                              const float* __restrict__ w4,
                                              const float* __restrict__ w5,
                                              unsigned short* __restrict__ Wt,
                                              const float* __restrict__ x,
                                              unsigned short* __restrict__ xb,
                                              const float* __restrict__ F,
                                              const float* __restrict__ Mf,
                                              unsigned short* __restrict__ phiev) {
    const int bid = blockIdx.x;
    const int tid = threadIdx.x;
    if (bid < 864) {
        const int z = bid / 144, rem = bid % 144;
        const float* W;
        switch (z) {
            case 0: W = w0; break;
            case 1: W = w1; break;
            case 2: W = w2; break;
            case 3: W = w3; break;
            case 4: W = w4; break;
            default: W = w5; break;
        }
        unsigned short* o = Wt + (size_t)z * D_ * D_;
        __shared__ float t[64][69];
        const int n0 = (rem % 12) * 64, k0 = (rem / 12) * 64;
        const int row = tid >> 4, c4 = (tid & 15) * 4;
#pragma unroll
        for (int i = 0; i < 4; ++i) {
            const float4 v = *reinterpret_cast<const float4*>(
                W + (size_t)(k0 + row + i * 16) * D_ + n0 + c4);
            t[row + i * 16][c4 + 0] = v.x;
            t[row + i * 16][c4 + 1] = v.y;
            t[row + i * 16][c4 + 2] = v.z;
            t[row + i * 16][c4 + 3] = v.w;
        }
        __syncthreads();
#pragma unroll
        for (int i = 0; i < 4; ++i) {
            const int nn = row + i * 16;
            ushort4 o4;
            o4.x = f2bf(t[c4 + 0][nn]);
            o4.y = f2bf(t[c4 + 1][nn]);
            o4.z = f2bf(t[c4 + 2][nn]);
            o4.w = f2bf(t[c4 + 3][nn]);
            *reinterpret_cast<ushort4*>(o + (size_t)(n0 + nn) * D_ + k0 + c4) = o4;
        }
    } else if (bid < 1632) {
        const int i8 = ((bid - 864) * 256 + tid) * 8;
        float4 f0 = *reinterpret_cast<const float4*>(x + i8);
        float4 f1 = *reinterpret_cast<const float4*>(x + i8 + 4);
        u16x8 p;
        p[0] = f2bf(f0.x); p[1] = f2bf(f0.y); p[2] = f2bf(f0.z); p[3] = f2bf(f0.w);
        p[4] = f2bf(f1.x); p[5] = f2bf(f1.y); p[6] = f2bf(f1.z); p[7] = f2bf(f1.w);
        *reinterpret_cast<u16x8*>(xb + i8) = p;
    } else {
        const int idx = (bid - 1632) * 256 + tid;    // over 512*768
        const int r = idx % R_;
        const int n = idx / R_;
        float acc = 0.f;
#pragma unroll
        for (int kk = 0; kk < K_; ++kk)
            acc += F[(2 * n) * K_ + kk] * Mf[kk * R_ + r];
        phiev[idx] = f2bf(2.f * acc);
    }
}

// ---------------------------------------------------------------------------
// bf16 MFMA GEMM core, 2-phase dbuf; mode 1 bf16 row, 2 transposed, 3 both.
// ---------------------------------------------------------------------------
template <int FM, int FN>
__device__ __forceinline__ void gemm_core(const unsigned short* __restrict__ A,
                                          const unsigned short* __restrict__ Bt,
                                          const float* __restrict__ bias,
                                          int mode,
                                          unsigned short* __restrict__ cbf,
                                          unsigned short* __restrict__ ct,
                                          int Kd, int bm, int bn, int tid) {
    constexpr int BM = 2 * FM * 16;
    constexpr int BN = 2 * FN * 16;
    constexpr int CTS = BM + 4;
    __shared__ __align__(16) unsigned short sm[2 * BM * 64 + 2 * BN * 64];
    unsigned short* As0 = sm;
    unsigned short* As1 = sm + BM * 64;
    unsigned short* Bs0 = sm + 2 * BM * 64;
    unsigned short* Bs1 = sm + 2 * BM * 64 + BN * 64;
    const int lane = tid & 63, wave = tid >> 6;
    const int wm = (wave >> 1) * (FM * 16), wn = (wave & 1) * (FN * 16);
    const int l15 = lane & 15, lg = lane >> 4;

    f32x4 acc[FM][FN] = {};

    auto stage = [&](int buf, int k0) {
        unsigned short* as = buf ? As1 : As0;
        unsigned short* bs = buf ? Bs1 : Bs0;
#pragma unroll
        for (int q = 0; q < FM; ++q) {
            const int s = q * 256 + tid;
            GLD_LDS16(A + (size_t)(bm + (s >> 3)) * Kd + k0 + (s & 7) * 8,
                      &as[s * 8]);
        }
#pragma unroll
        for (int q = 0; q < FN; ++q) {
            const int s = q * 256 + tid;
            GLD_LDS16(Bt + (size_t)(bn + (s >> 3)) * Kd + k0 + (s & 7) * 8,
                      &bs[s * 8]);
        }
    };

    stage(0, 0);
    __syncthreads();
    int cur = 0;
    const int nt = Kd / 64;
    for (int t = 0; t < nt; ++t) {
        if (t + 1 < nt) stage(cur ^ 1, (t + 1) * 64);
        const unsigned short* as = cur ? As1 : As0;
        const unsigned short* bs = cur ? Bs1 : Bs0;
#pragma unroll
        for (int ks = 0; ks < 2; ++ks) {
            const int kb = ks * 32 + lg * 8;
            bf16x8 a[FM], b[FN];
#pragma unroll
            for (int f = 0; f < FM; ++f)
                a[f] = *reinterpret_cast<const bf16x8*>(&as[(wm + f * 16 + l15) * 64 + kb]);
#pragma unroll
            for (int f = 0; f < FN; ++f)
                b[f] = *reinterpret_cast<const bf16x8*>(&bs[(wn + f * 16 + l15) * 64 + kb]);
#pragma unroll
            for (int fm = 0; fm < FM; ++fm)
#pragma unroll
                for (int fn = 0; fn < FN; ++fn)
                    acc[fm][fn] = __builtin_amdgcn_mfma_f32_16x16x32_bf16(
                        a[fm], b[fn], acc[fm][fn], 0, 0, 0);
        }
        __syncthreads();
        cur ^= 1;
    }

#pragma unroll
    for (int fm = 0; fm < FM; ++fm)
#pragma unroll
        for (int fn = 0; fn < FN; ++fn) {
            const int cl = wn + fn * 16 + l15;
            const int col = bn + cl;
            const float bv = bias ? bias[col] : 0.f;
            const int rl = wm + fm * 16 + lg * 4;
            const int r0 = bm + rl;
            f32x4 v = acc[fm][fn];
            v[0] += bv; v[1] += bv; v[2] += bv; v[3] += bv;
            if (mode & 1) {
#pragma unroll
                for (int j = 0; j < 4; ++j)
                    cbf[(size_t)(r0 + j) * D_ + col] = f2bf(v[j]);
            }
            if (mode & 2) {
                *reinterpret_cast<ushort4*>(&sm[cl * CTS + rl]) = pack4(v);
            }
        }

    if (mode & 2) {
        __syncthreads();
        const int bI = bm >> 10, l0 = bm & 1023;
#pragma unroll
        for (int q = 0; q < BN * BM / 8 / 256; ++q) {
            const int slot = q * 256 + tid;
            const int cl = slot / (BM / 8), seg = slot % (BM / 8);
            const int gcol = bn + cl;
            const int h = gcol >> 6, n = gcol & 63;
            *reinterpret_cast<u16x8*>(
                ct + (((size_t)bI * NH_ + h) * 64 + n) * (size_t)L_ + l0 + seg * 8) =
                *reinterpret_cast<const u16x8*>(&sm[cl * CTS + seg * 8]);
        }
    }
}

// 5 x-projections; z selects output format.
__global__ __launch_bounds__(256) void k_gemm5(const unsigned short* __restrict__ A,
                                               const unsigned short* __restrict__ wt,
                                               const float* __restrict__ bq,
                                               const float* __restrict__ bk,
                                               const float* __restrict__ bv,
                                               const float* __restrict__ bg,
                                               unsigned short* __restrict__ ubf,
                                               unsigned short* __restrict__ qbf,
                                               unsigned short* __restrict__ ktb,
                                               unsigned short* __restrict__ vbf,
                                               unsigned short* __restrict__ vtb,
                                               unsigned short* __restrict__ gbf) {
    const int z = blockIdx.z;
    const float* bias = nullptr;
    int mode = 1;
    unsigned short* cbf = nullptr; unsigned short* ct = nullptr;
    switch (z) {
        case 0: mode = 1; cbf = ubf; bias = nullptr; break;
        case 1: mode = 1; cbf = qbf; bias = bq; break;
        case 2: mode = 2; ct = ktb; bias = bk; break;
        case 3: mode = 3; cbf = vbf; ct = vtb; bias = bv; break;
        default: mode = 1; cbf = gbf; bias = bg; break;
    }
    gemm_core<4, 4>(A, wt + (size_t)z * D_ * D_, bias, mode, cbf, ct,
                    D_, blockIdx.y * 128, blockIdx.x * 128, threadIdx.x);
}

// ---------------------------------------------------------------------------
// k_attnconv (768 blocks x 256 thr):
//   blocks [0,384): chunked MFMA attention -> yab (bf16, pre-gate)
//   blocks [384,768): load-balanced parity conv -> xtb (bf16, no gate)
//     conv: 384 blocks = rthird(3) x bp(4) x pair(32); 256 thr = 8 stripe-
//     groups x 32 r8-lanes; block does m-groups pi and 63-pi (65 stripes).
// ---------------------------------------------------------------------------
__global__ __launch_bounds__(256) void k_attnconv(const unsigned short* __restrict__ qbf,
                                                  const unsigned short* __restrict__ vbf,
                                                  const unsigned short* __restrict__ ktb,
                                                  const unsigned short* __restrict__ vtb,
                                                  unsigned short* __restrict__ yab,
                                                  const unsigned short* __restrict__ ubf,
                                                  const unsigned short* __restrict__ phiev,
                                                  unsigned short* __restrict__ xtb) {
    __shared__ __align__(16) char smem_raw[75776];
    unsigned short* sm16 = (unsigned short*)smem_raw;
    const int tid = threadIdx.x;

    if (blockIdx.x >= 384) {
        // ---------------- conv part ----------------
        const int cu = (int)blockIdx.x - 384;      // 0..383
        const int rt = cu % 3;                     // r-third
        const int bpi = cu / 3;                    // 0..127
        const int bp = bpi & 3;
        const int pi = bpi >> 2;                   // pair 0..31
        const int b = bp >> 1, p = bp & 1;
        const int g = tid >> 5, lr = tid & 31;     // 8 groups x 32 lanes
        const int r = (rt * 32 + lr) * 8;
        u16x8* red = (u16x8*)sm16;                 // [8][8][32] = 32768 B

#pragma unroll
        for (int half = 0; half < 2; ++half) {
            const int mg = half ? (63 - pi) : pi;
            const int m0 = mg * 8;
            const int S = mg + 1;                  // full stripes
            f32x8 acc[8] = {};
            f32x8 w[8] = {};

            for (int s = g; s < S; s += 8) {
                const int i0 = s * 8;
                if (s > 0) {
#pragma unroll
                    for (int j = 1; j <= 7; ++j)
                        w[(8 - j) & 7] = bf2f8(*reinterpret_cast<const u16x8*>(
                            phiev + (size_t)(i0 - j) * R_ + r));
                }
                const unsigned short* pp = phiev + (size_t)i0 * R_ + r;
                const unsigned short* up =
                    ubf + ((size_t)(b * L_) + (size_t)(2 * (m0 + 7 - i0) + p)) * R_ + r;
#pragma unroll
                for (int k = 0; k < 8; ++k) {
                    const u16x8 pv = *reinterpret_cast<const u16x8*>(pp);
                    const u16x8 uv = *reinterpret_cast<const u16x8*>(up);
                    w[k] = bf2f8(pv);
                    const f32x8 fu = bf2f8(uv);
#pragma unroll
                    for (int a = 0; a < 8; ++a)
                        acc[a] += w[(k + a + 1) & 7] * fu;
                    pp += R_;
                    up -= 2 * R_;
                }
            }

#pragma unroll
            for (int a = 0; a < 8; ++a) red[(g * 8 + a) * 32 + lr] = pack8(acc[a]);
            __syncthreads();

            // 256 threads reduce 8 rows x 32 lanes: thread (g,lr) -> row g
            {
                f32x8 sres = {};
#pragma unroll
                for (int g2 = 0; g2 < 8; ++g2)
                    sres += bf2f8(red[(g2 * 8 + g) * 32 + lr]);
                const size_t idx =
                    ((size_t)(b * L_) + (size_t)(2 * (m0 + g) + p)) * R_ + r;
                *reinterpret_cast<u16x8*>(xtb + idx) = pack8(sres);
            }
            if (half == 0) __syncthreads();        // red reused next half
        }
        return;
    }

    // ---------------- attn part ----------------
    const int c = blockIdx.x & 15, h = (blockIdx.x >> 4) % NH_, b = blockIdx.x / (16 * NH_);
    unsigned short* Qs  = sm16;
    unsigned short* Vs  = sm16 + 4096;
    unsigned short* Kc  = sm16 + 8192;
    unsigned short* Tk0 = sm16 + 12288;
    unsigned short* Tk1 = sm16 + 16384;
    unsigned short* Tv0 = sm16 + 20480;
    unsigned short* Tv1 = sm16 + 24576;
    unsigned short* Sl  = sm16 + 28672;
    unsigned short* Hl  = sm16 + 33280;

    const int lane = tid & 63, wave = tid >> 6;
    const int wr = (wave >> 1) * 32, wc = (wave & 1) * 32;
    const int l15 = lane & 15, lg = lane >> 4;

    {
        const size_t rowbase = ((size_t)(b * L_ + c * CS_)) * D_ + h * HD_;
        const size_t tbase = ((size_t)(b * NH_ + h)) * 64 * (size_t)L_ + c * 64;
#pragma unroll
        for (int q2 = 0; q2 < 2; ++q2) {
            const int s = q2 * 256 + tid;
            const int row = s >> 3, c8 = s & 7;
            GLD_LDS16(qbf + rowbase + (size_t)row * D_ + c8 * 8, &Qs[s * 8]);
            GLD_LDS16(vbf + rowbase + (size_t)row * D_ + c8 * 8, &Vs[s * 8]);
            GLD_LDS16(ktb + tbase + (size_t)row * L_ + c8 * 8, &Kc[s * 8]);
        }
    }

    auto stage_t = [&](int buf, int cc) {
        unsigned short* tk = buf ? Tk1 : Tk0;
        unsigned short* tv = buf ? Tv1 : Tv0;
        const size_t tb2 = ((size_t)(b * NH_ + h)) * 64 * (size_t)L_ + cc * 64;
#pragma unroll
        for (int q2 = 0; q2 < 2; ++q2) {
            const int s = q2 * 256 + tid;
            const int row = s >> 3, c8 = s & 7;
            GLD_LDS16(ktb + tb2 + (size_t)row * L_ + c8 * 8, &tk[s * 8]);
            GLD_LDS16(vtb + tb2 + (size_t)row * L_ + c8 * 8, &tv[s * 8]);
        }
    };

    if (c > 0) stage_t(0, 0);
    __syncthreads();

    f32x4 hacc[2][2] = {};
    int cur = 0;
    for (int cc = 0; cc < c; ++cc) {
        if (cc + 1 < c) stage_t(cur ^ 1, cc + 1);
        const unsigned short* tk = cur ? Tk1 : Tk0;
        const unsigned short* tv = cur ? Tv1 : Tv0;
#pragma unroll
        for (int ks = 0; ks < 2; ++ks) {
            const int kb = ks * 32 + lg * 8;
            bf16x8 av[2], bk[2];
#pragma unroll
            for (int f = 0; f < 2; ++f) {
                av[f] = *reinterpret_cast<const bf16x8*>(&tv[(wr + f * 16 + l15) * 64 + kb]);
                bk[f] = *reinterpret_cast<const bf16x8*>(&tk[(wc + f * 16 + l15) * 64 + kb]);
            }
#pragma unroll
            for (int fm = 0; fm < 2; ++fm)
#pragma unroll
                for (int fn = 0; fn < 2; ++fn)
                    hacc[fm][fn] = __builtin_amdgcn_mfma_f32_16x16x32_bf16(
                        av[fm], bk[fn], hacc[fm][fn], 0, 0, 0);
        }
        __syncthreads();
        cur ^= 1;
    }

    if (c > 0) {
#pragma unroll
        for (int fm = 0; fm < 2; ++fm)
#pragma unroll
            for (int fn = 0; fn < 2; ++fn) {
                const int n = wc + fn * 16 + l15;
                const int p0 = wr + fm * 16 + lg * 4;
                *reinterpret_cast<ushort4*>(&Hl[n * 72 + p0]) = pack4(hacc[fm][fn]);
            }
    }

    {
        f32x4 sacc[2][2] = {};
#pragma unroll
        for (int ks = 0; ks < 2; ++ks) {
            const int kb = ks * 32 + lg * 8;
            bf16x8 av[2], bq[2];
#pragma unroll
            for (int f = 0; f < 2; ++f) {
                av[f] = *reinterpret_cast<const bf16x8*>(&Vs[(wr + f * 16 + l15) * 64 + kb]);
                bq[f] = *reinterpret_cast<const bf16x8*>(&Qs[(wc + f * 16 + l15) * 64 + kb]);
            }
#pragma unroll
            for (int fm = 0; fm < 2; ++fm)
#pragma unroll
                for (int fn = 0; fn < 2; ++fn)
                    sacc[fm][fn] = __builtin_amdgcn_mfma_f32_16x16x32_bf16(
                        av[fm], bq[fn], sacc[fm][fn], 0, 0, 0);
        }
#pragma unroll
        for (int fm = 0; fm < 2; ++fm)
#pragma unroll
            for (int fn = 0; fn < 2; ++fn) {
                const int t = wc + fn * 16 + l15;
                const int s0 = wr + fm * 16 + lg * 4;
#pragma unroll
                for (int j = 0; j < 4; ++j)
                    if (s0 + j > t) sacc[fm][fn][j] = 0.f;
                *reinterpret_cast<ushort4*>(&Sl[t * 72 + s0]) = pack4(sacc[fm][fn]);
            }
    }
    __syncthreads();

    f32x4 yacc[2][2] = {};
#pragma unroll
    for (int ks = 0; ks < 2; ++ks) {
        const int kb = ks * 32 + lg * 8;
        bf16x8 ak[2], bs[2];
#pragma unroll
        for (int f = 0; f < 2; ++f) {
            ak[f] = *reinterpret_cast<const bf16x8*>(&Kc[(wr + f * 16 + l15) * 64 + kb]);
            bs[f] = *reinterpret_cast<const bf16x8*>(&Sl[(wc + f * 16 + l15) * 72 + kb]);
        }
#pragma unroll
        for (int fm = 0; fm < 2; ++fm)
#pragma unroll
            for (int fn = 0; fn < 2; ++fn)
                yacc[fm][fn] = __builtin_amdgcn_mfma_f32_16x16x32_bf16(
                    ak[fm], bs[fn], yacc[fm][fn], 0, 0, 0);
    }
    if (c > 0) {
#pragma unroll
        for (int ks = 0; ks < 2; ++ks) {
            const int kb = ks * 32 + lg * 8;
            bf16x8 ah[2], bq[2];
#pragma unroll
            for (int f = 0; f < 2; ++f) {
                ah[f] = *reinterpret_cast<const bf16x8*>(&Hl[(wr + f * 16 + l15) * 72 + kb]);
                bq[f] = *reinterpret_cast<const bf16x8*>(&Qs[(wc + f * 16 + l15) * 64 + kb]);
            }
#pragma unroll
            for (int fm = 0; fm < 2; ++fm)
#pragma unroll
                for (int fn = 0; fn < 2; ++fn)
                    yacc[fm][fn] = __builtin_amdgcn_mfma_f32_16x16x32_bf16(
                        ah[fm], bq[fn], yacc[fm][fn], 0, 0, 0);
        }
    }

#pragma unroll
    for (int fm = 0; fm < 2; ++fm)
#pragma unroll
        for (int fn = 0; fn < 2; ++fn) {
            const int n0 = wr + fm * 16 + lg * 4;
            const int t = wc + fn * 16 + l15;
            const size_t idx = ((size_t)(b * L_ + c * CS_ + t)) * D_ + h * HD_ + n0;
            *reinterpret_cast<ushort4*>(yab + idx) = pack4(yacc[fm][fn]);
        }
}

// ---------------------------------------------------------------------------
// k_outgemm: out = gate(xt, ya, g) @ Wo^T + bo, gate fused in A-staging.
// ---------------------------------------------------------------------------
__global__ __launch_bounds__(256) void k_outgemm(const unsigned short* __restrict__ xtb,
                                                 const unsigned short* __restrict__ yab,
                                                 const unsigned short* __restrict__ gbf,
                                                 const unsigned short* __restrict__ Bt,
                                                 const float* __restrict__ bias,
                                                 float* __restrict__ C) {
    constexpr int BM = 32, BN = 64;
    __shared__ __align__(16) unsigned short sm[2 * BM * 64 + 2 * BN * 64];
    unsigned short* As0 = sm;
    unsigned short* As1 = sm + BM * 64;
    unsigned short* Bs0 = sm + 2 * BM * 64;
    unsigned short* Bs1 = sm + 2 * BM * 64 + BN * 64;
    const int tid = threadIdx.x;
    const int bm = blockIdx.y * BM, bn = blockIdx.x * BN;
    const int lane = tid & 63, wave = tid >> 6;
    const int wm = (wave >> 1) * 16, wn = (wave & 1) * 32;
    const int l15 = lane & 15, lg = lane >> 4;

    f32x4 acc[1][2] = {};

    auto stage = [&](int buf, int k0) {
        {
            unsigned short* as = buf ? As1 : As0;
            const int row = tid >> 3, c8 = tid & 7;
            const size_t idx = (size_t)(bm + row) * D_ + k0 + c8 * 8;
            const f32x8 xv = bf2f8(*reinterpret_cast<const u16x8*>(xtb + idx));
            const f32x8 yv = bf2f8(*reinterpret_cast<const u16x8*>(yab + idx));
            const f32x8 gv = bf2f8(*reinterpret_cast<const u16x8*>(gbf + idx));
            f32x8 o;
#pragma unroll
            for (int e = 0; e < 8; ++e) {
                const float sg = 1.f / (1.f + expf(-gv[e]));
                o[e] = xv[e] + (yv[e] - xv[e]) * sg;
            }
            *reinterpret_cast<u16x8*>(&as[tid * 8]) = pack8(o);
        }
        {
            unsigned short* bs = buf ? Bs1 : Bs0;
#pragma unroll
            for (int q = 0; q < 2; ++q) {
                const int s = q * 256 + tid;
                GLD_LDS16(Bt + (size_t)(bn + (s >> 3)) * D_ + k0 + (s & 7) * 8,
                          &bs[s * 8]);
            }
        }
    };

    stage(0, 0);
    __syncthreads();
    int cur = 0;
    const int nt = D_ / 64;
    for (int t = 0; t < nt; ++t) {
        if (t + 1 < nt) stage(cur ^ 1, (t + 1) * 64);
        const unsigned short* as = cur ? As1 : As0;
        const unsigned short* bs = cur ? Bs1 : Bs0;
#pragma unroll
        for (int ks = 0; ks < 2; ++ks) {
            const int kb = ks * 32 + lg * 8;
            bf16x8 a0 = *reinterpret_cast<const bf16x8*>(&as[(wm + l15) * 64 + kb]);
            bf16x8 b0 = *reinterpret_cast<const bf16x8*>(&bs[(wn + l15) * 64 + kb]);
            bf16x8 b1 = *reinterpret_cast<const bf16x8*>(&bs[(wn + 16 + l15) * 64 + kb]);
            acc[0][0] = __builtin_amdgcn_mfma_f32_16x16x32_bf16(a0, b0, acc[0][0], 0, 0, 0);
            acc[0][1] = __builtin_amdgcn_mfma_f32_16x16x32_bf16(a0, b1, acc[0][1], 0, 0, 0);
        }
        __syncthreads();
        cur ^= 1;
    }

#pragma unroll
    for (int fn = 0; fn < 2; ++fn) {
        const int col = bn + wn + fn * 16 + l15;
        const float bv = bias[col];
        const int r0 = bm + wm + lg * 4;
#pragma unroll
        for (int j = 0; j < 4; ++j)
            C[(size_t)(r0 + j) * D_ + col] = acc[0][fn][j] + bv;
    }
}

// ---------------------------------------------------------------------------
extern "C" void kernel_launch(void* const* d_in, const int* in_sizes, int n_in,
                              void* d_out, int out_size, void* d_ws, size_t ws_size,
                              hipStream_t stream) {
    const float* x    = (const float*)d_in[0];
    const float* stu  = (const float*)d_in[1];
    const float* Mi   = (const float*)d_in[2];
    const float* Mf   = (const float*)d_in[3];
    const float* wq_w = (const float*)d_in[4];
    const float* wq_b = (const float*)d_in[5];
    const float* wk_w = (const float*)d_in[6];
    const float* wk_b = (const float*)d_in[7];
    const float* wv_w = (const float*)d_in[8];
    const float* wv_b = (const float*)d_in[9];
    const float* wg_w = (const float*)d_in[10];
    const float* wg_b = (const float*)d_in[11];
    const float* wo_w = (const float*)d_in[12];
    const float* wo_b = (const float*)d_in[13];
    float* out = (float*)d_out;

    char* ws = (char*)d_ws;
    size_t o = 0;
    const size_t WSZ = (size_t)D_ * D_;
    unsigned short* wbf   = (unsigned short*)(ws + o); o += 6 * WSZ * 2;
    unsigned short* xbf   = (unsigned short*)(ws + o); o += (size_t)B_ * L_ * D_ * 2;
    unsigned short* qbf   = (unsigned short*)(ws + o); o += (size_t)B_ * L_ * D_ * 2;
    unsigned short* vbf   = (unsigned short*)(ws + o); o += (size_t)B_ * L_ * D_ * 2;
    unsigned short* ubf   = (unsigned short*)(ws + o); o += (size_t)B_ * L_ * D_ * 2;
    unsigned short* gbf   = (unsigned short*)(ws + o); o += (size_t)B_ * L_ * D_ * 2;
    unsigned short* yab   = (unsigned short*)(ws + o); o += (size_t)B_ * L_ * D_ * 2;
    unsigned short* xtb   = (unsigned short*)(ws + o); o += (size_t)B_ * L_ * D_ * 2;
    unsigned short* ktb   = (unsigned short*)(ws + o); o += (size_t)B_ * NH_ * 64 * L_ * 2;
    unsigned short* vtb   = (unsigned short*)(ws + o); o += (size_t)B_ * NH_ * 64 * L_ * 2;
    unsigned short* phiev = (unsigned short*)(ws + o); o += (size_t)(L_ / 2) * R_ * 2;

    unsigned short* wo_t = wbf + 5 * WSZ;

    const dim3 blk(256);

    k_prep<<<dim3(3168), blk, 0, stream>>>(Mi, wq_w, wk_w, wv_w, wg_w, wo_w, wbf,
                                           x, xbf, stu, Mf, phiev);

    k_gemm5<<<dim3(D_ / 128, (B_ * L_) / 128, 5), blk, 0, stream>>>(
        xbf, wbf, wq_b, wk_b, wv_b, wg_b, ubf, qbf, ktb, vbf, vtb, gbf);

    k_attnconv<<<dim3(768), blk, 0, stream>>>(qbf, vbf, ktb, vtb, yab,
                                              ubf, phiev, xtb);

    k_outgemm<<<dim3(D_ / 64, (B_ * L_) / 32), blk, 0, stream>>>(
        xtb, yab, gbf, wo_t, wo_b, out);
}